// Round 8
// baseline (209.412 us; speedup 1.0000x reference)
//
#include <hip/hip_runtime.h>
#include <math.h>

// B=1, I=J=256, C=128, H=4, CH=32
#define NI 256
#define NJ 256
#define NC 128
#define NH 4
#define NCH 32
#define TOKS ((long)NI * NJ)

typedef __attribute__((ext_vector_type(8)))  __bf16        bf16x8;
typedef __attribute__((ext_vector_type(8)))  unsigned short u16x8;
typedef __attribute__((ext_vector_type(4)))  unsigned int   u32x4;
typedef __attribute__((ext_vector_type(16))) float         f32x16;

__device__ __forceinline__ unsigned short f2bf(float f) {
    unsigned u = __builtin_bit_cast(unsigned, f);
    u += 0x7fffu + ((u >> 16) & 1u);          // RNE
    return (unsigned short)(u >> 16);
}
__device__ __forceinline__ float bf2f(unsigned short s) {
    return __builtin_bit_cast(float, ((unsigned)s) << 16);
}
__device__ __forceinline__ float exp2_fast(float x) {
    float r;
    asm("v_exp_f32 %0, %1" : "=v"(r) : "v"(x));   // D = 2^S0
    return r;
}
__device__ __forceinline__ f32x16 fzero16() {
    f32x16 z;
#pragma unroll
    for (int r = 0; r < 16; ++r) z[r] = 0.f;
    return z;
}
__device__ __forceinline__ f32x16 mfma16(bf16x8 a, bf16x8 b, f32x16 c) {
    return __builtin_amdgcn_mfma_f32_32x32x16_bf16(a, b, c, 0, 0, 0);
}

#define LOG2E 1.4426950408889634f
#define QSCALE 0.25503486f   // CH^-0.5 * log2e

// ---------------------------------------------------------------------------
// Kernel 0: transpose+convert weights to bf16. w_tri pre-scaled by log2e.
// ---------------------------------------------------------------------------
__global__ __launch_bounds__(256) void convert_weights(
    const float* __restrict__ wq, const float* __restrict__ wk,
    const float* __restrict__ wv, const float* __restrict__ wg,
    const float* __restrict__ wo, const float* __restrict__ w_tri,
    unsigned short* __restrict__ Wt_all, unsigned short* __restrict__ Wto,
    unsigned short* __restrict__ Wtri_pad)
{
    int id = blockIdx.x * 256 + threadIdx.x;          // 0..86015
    if (id < 4 * 16384) {
        int m = id >> 14, r = id & 16383;
        int kk = r >> 7, c = r & 127;
        const float* W = (m == 0) ? wq : (m == 1) ? wk : (m == 2) ? wv : wg;
        Wt_all[(m * 128 + c) * 128 + kk] = f2bf(W[kk * 128 + c]);
    } else if (id < 5 * 16384) {
        int r = id - 4 * 16384;
        int kk = r >> 7, c = r & 127;
        Wto[c * 128 + kk] = f2bf(wo[kk * 128 + c]);
    } else {
        int r = id - 5 * 16384;                        // 0..4095
        int col = r >> 7, kk = r & 127;
        Wtri_pad[col * 128 + kk] = (col < NH) ? f2bf(w_tri[kk * NH + col] * LOG2E)
                                              : (unsigned short)0;
    }
}

// ---------------------------------------------------------------------------
// Kernel 1: LayerNorm + tri bias via MFMA -> tswz (pre-swizzled).
// Slimmed ln_proj: q/k/v/g moved into the fused attention kernel.
// ---------------------------------------------------------------------------
#define XNP 136
__global__ __launch_bounds__(256, 2) void ln_tri(
    const float* __restrict__ x, const float* __restrict__ ln_w, const float* __restrict__ ln_b,
    const unsigned short* __restrict__ Wtri_pad, float* __restrict__ tswz)
{
    __shared__ unsigned short xn[64 * XNP];   // ~17.4 KB
    const int tid = threadIdx.x;
    const long tok0 = (long)blockIdx.x * 64;

    const int lane8 = tid & 7;
#pragma unroll
    for (int p = 0; p < 2; ++p) {
        const int t = p * 32 + (tid >> 3);
        const float4* xrow = (const float4*)(x + (tok0 + t) * NC + lane8 * 16);
        float4 xv[4];
        float s = 0.f;
#pragma unroll
        for (int u = 0; u < 4; ++u) {
            xv[u] = xrow[u];
            s += xv[u].x + xv[u].y + xv[u].z + xv[u].w;
        }
#pragma unroll
        for (int off = 4; off; off >>= 1) s += __shfl_down(s, off, 8);
        const float mu = __shfl(s, 0, 8) * (1.f / (float)NC);
        float s2 = 0.f;
#pragma unroll
        for (int u = 0; u < 4; ++u) {
            float dx;
            dx = xv[u].x - mu; s2 += dx * dx;
            dx = xv[u].y - mu; s2 += dx * dx;
            dx = xv[u].z - mu; s2 += dx * dx;
            dx = xv[u].w - mu; s2 += dx * dx;
        }
#pragma unroll
        for (int off = 4; off; off >>= 1) s2 += __shfl_down(s2, off, 8);
        const float rstd = rsqrtf(__shfl(s2, 0, 8) * (1.f / (float)NC) + 1e-5f);
#pragma unroll
        for (int u = 0; u < 4; ++u) {
            const int c = lane8 * 16 + u * 4;
            const float4 lw = *(const float4*)(ln_w + c);
            const float4 lb = *(const float4*)(ln_b + c);
            float o0 = (xv[u].x - mu) * rstd * lw.x + lb.x;
            float o1 = (xv[u].y - mu) * rstd * lw.y + lb.y;
            float o2 = (xv[u].z - mu) * rstd * lw.z + lb.z;
            float o3 = (xv[u].w - mu) * rstd * lw.w + lb.w;
            unsigned p0 = (unsigned)f2bf(o0) | ((unsigned)f2bf(o1) << 16);
            unsigned p1 = (unsigned)f2bf(o2) | ((unsigned)f2bf(o3) << 16);
            *(unsigned*)&xn[t * XNP + c]     = p0;
            *(unsigned*)&xn[t * XNP + c + 2] = p1;
        }
    }
    __syncthreads();

    const int L = tid & 63, lh = L >> 5, lc = L & 31;
    f32x16 accT[2];
    accT[0] = fzero16();
    accT[1] = fzero16();

#pragma unroll
    for (int k0 = 0; k0 < 8; ++k0) {
        bf16x8 a0 = *(const bf16x8*)&xn[(lc)      * XNP + k0 * 16 + lh * 8];
        bf16x8 a1 = *(const bf16x8*)&xn[(32 + lc) * XNP + k0 * 16 + lh * 8];
        bf16x8 bt = *(const bf16x8*)&Wtri_pad[lc * 128 + k0 * 16 + lh * 8];
        accT[0] = mfma16(a0, bt, accT[0]);
        accT[1] = mfma16(a1, bt, accT[1]);
    }

    const int a_row = (int)(tok0 >> 8);
    const int b0    = (int)(tok0 & 255);
    if (lc < NH) {
        const int qt_i = a_row >> 5;
        const int lsw  = ((a_row & 31) + 32 * lh) * 16;
#pragma unroll
        for (int mt = 0; mt < 2; ++mt) {
            float* dst = tswz + ((long)((lc * 8 + qt_i) * 8 + (b0 >> 5) + mt)) * 1024 + lsw;
#pragma unroll
            for (int u = 0; u < 4; ++u)
                *(float4*)(dst + u * 4) = make_float4(accT[mt][4*u],   accT[mt][4*u+1],
                                                      accT[mt][4*u+2], accT[mt][4*u+3]);
        }
    }
}

// ---------------------------------------------------------------------------
// Kernel 2: FUSED LayerNorm + projections + attention + gating + out-proj.
// One block per row i: 512 threads = 8 waves; wave w owns token tile w
// (32 tokens), serving as both its q-tile and its k/v contribution.
// Per head: proj in registers (swapped-operand MFMA gives attn-ready
// layouts), scatter k->Ks, v->Vt in LDS, q assembled in-register via the
// proven shfl_xor(32) idiom, g kept in f32 regs (no bf16 round-trip).
// t-loop / gate / Wo-accumulate / epilogue are the proven R5 code.
// ---------------------------------------------------------------------------
#define KSP 40    // Ks row stride (shorts)
#define VTP 264   // Vt row stride (shorts)
#define OSP 36    // outs row stride (floats)
__global__ __launch_bounds__(512, 2) void attn_mega(
    const float* __restrict__ x, const float* __restrict__ ln_w, const float* __restrict__ ln_b,
    const unsigned short* __restrict__ Wt_all, const float* __restrict__ tswz,
    const float* __restrict__ mask, const unsigned short* __restrict__ Wto,
    const float* __restrict__ bg, const float* __restrict__ bo,
    float* __restrict__ out)
{
    __shared__ char smem[108032];
    // [0..69632)        : xn [256][136] bf16 (LN result; epilogue reuses as outs)
    unsigned short* xn = (unsigned short*)smem;
    unsigned short* Ks = (unsigned short*)(smem + 69632);    // 256*40*2 = 20480
    unsigned short* Vt = (unsigned short*)(smem + 90112);    // 32*264*2 = 16896
    float*       maskb = (float*)(smem + 107008);            // 1024
    float*        outs = (float*)smem;                       // 256*36*4 = 36864

    const int i = blockIdx.x;
    const int tid = threadIdx.x;                 // 0..511
    const int w = tid >> 6, L = tid & 63, lh = L >> 5, lc = L & 31;

    if (tid < NJ) maskb[tid] = (1.0e9f * LOG2E) * (mask[i * NJ + tid] - 1.0f);

    // ---- LayerNorm the row's 256 tokens into LDS (8 lanes per token) ----
    const int lane8 = tid & 7;
#pragma unroll
    for (int p = 0; p < 4; ++p) {
        const int t = p * 64 + (tid >> 3);
        const float4* xrow = (const float4*)(x + ((long)i * NJ + t) * NC + lane8 * 16);
        float4 xv[4];
        float s = 0.f;
#pragma unroll
        for (int u = 0; u < 4; ++u) {
            xv[u] = xrow[u];
            s += xv[u].x + xv[u].y + xv[u].z + xv[u].w;
        }
#pragma unroll
        for (int off = 4; off; off >>= 1) s += __shfl_down(s, off, 8);
        const float mu = __shfl(s, 0, 8) * (1.f / (float)NC);
        float s2 = 0.f;
#pragma unroll
        for (int u = 0; u < 4; ++u) {
            float dx;
            dx = xv[u].x - mu; s2 += dx * dx;
            dx = xv[u].y - mu; s2 += dx * dx;
            dx = xv[u].z - mu; s2 += dx * dx;
            dx = xv[u].w - mu; s2 += dx * dx;
        }
#pragma unroll
        for (int off = 4; off; off >>= 1) s2 += __shfl_down(s2, off, 8);
        const float rstd = rsqrtf(__shfl(s2, 0, 8) * (1.f / (float)NC) + 1e-5f);
#pragma unroll
        for (int u = 0; u < 4; ++u) {
            const int c = lane8 * 16 + u * 4;
            const float4 lw = *(const float4*)(ln_w + c);
            const float4 lb = *(const float4*)(ln_b + c);
            float o0 = (xv[u].x - mu) * rstd * lw.x + lb.x;
            float o1 = (xv[u].y - mu) * rstd * lw.y + lb.y;
            float o2 = (xv[u].z - mu) * rstd * lw.z + lb.z;
            float o3 = (xv[u].w - mu) * rstd * lw.w + lb.w;
            unsigned p0 = (unsigned)f2bf(o0) | ((unsigned)f2bf(o1) << 16);
            unsigned p1 = (unsigned)f2bf(o2) | ((unsigned)f2bf(o3) << 16);
            *(unsigned*)&xn[t * XNP + c]     = p0;
            *(unsigned*)&xn[t * XNP + c + 2] = p1;
        }
    }
    __syncthreads();

    int rowl[16];
#pragma unroll
    for (int r = 0; r < 16; ++r) rowl[r] = (r & 3) + 8 * (r >> 2) + 4 * lh;

    f32x16 outacc[4];
#pragma unroll
    for (int ct = 0; ct < 4; ++ct) outacc[ct] = fzero16();

#pragma unroll
    for (int h = 0; h < NH; ++h) {
        // ---- per-head projections (registers only; overlaps prev t-loop) ----
        f32x16 qacc = fzero16(), kacc = fzero16(), vacc = fzero16(), gacc = fzero16();
        const unsigned short* Wq = Wt_all + ((0 * 128 + h * 32 + lc) * 128);
        const unsigned short* Wk = Wt_all + ((1 * 128 + h * 32 + lc) * 128);
        const unsigned short* Wv = Wt_all + ((2 * 128 + h * 32 + lc) * 128);
        const unsigned short* Wg = Wt_all + ((3 * 128 + h * 32 + lc) * 128);
        const unsigned short* xnrow = xn + (w * 32 + lc) * XNP;
#pragma unroll
        for (int k0 = 0; k0 < 8; ++k0) {
            const int ko = k0 * 16 + lh * 8;
            const bf16x8 xf  = *(const bf16x8*)&xnrow[ko];
            const bf16x8 wqf = *(const bf16x8*)&Wq[ko];
            const bf16x8 wkf = *(const bf16x8*)&Wk[ko];
            const bf16x8 wvf = *(const bf16x8*)&Wv[ko];
            const bf16x8 wgf = *(const bf16x8*)&Wg[ko];
            qacc = mfma16(wqf, xf, qacc);     // swapped: C[reg=ch][lane=token]
            kacc = mfma16(wkf, xf, kacc);     // swapped
            vacc = mfma16(xf, wvf, vacc);     // normal:  C[reg=token][lane=ch]
            gacc = mfma16(wgf, xf, gacc);     // swapped
        }

        // q: scale + pack pairs, assemble B-frags in-register (lane^32 idiom)
        unsigned pkq[8];
#pragma unroll
        for (int j = 0; j < 8; ++j)
            pkq[j] = (unsigned)f2bf(qacc[2*j] * QSCALE)
                   | ((unsigned)f2bf(qacc[2*j+1] * QSCALE) << 16);
        bf16x8 a0, a1;
#pragma unroll
        for (int ss = 0; ss < 2; ++ss) {
            const unsigned give0 = lh ? pkq[4*ss]     : pkq[4*ss + 2];
            const unsigned give1 = lh ? pkq[4*ss + 1] : pkq[4*ss + 3];
            const unsigned t0 = __shfl_xor(give0, 32);
            const unsigned t1 = __shfl_xor(give1, 32);
            u32x4 bw;
            bw[0] = lh ? t0 : pkq[4*ss];
            bw[1] = lh ? t1 : pkq[4*ss + 1];
            bw[2] = lh ? pkq[4*ss + 2] : t0;
            bw[3] = lh ? pkq[4*ss + 3] : t1;
            if (ss == 0) a0 = __builtin_bit_cast(bf16x8, bw);
            else         a1 = __builtin_bit_cast(bf16x8, bw);
        }

        // g: sigmoid in f32 regs (reg r <-> ch rowl(r), matches O layout)
        float gq[16];
#pragma unroll
        for (int gg = 0; gg < 4; ++gg) {
            const float4 b4 = *(const float4*)(bg + h * 32 + gg * 8 + 4 * lh);
            gq[4*gg + 0] = __builtin_amdgcn_rcpf(1.f + __expf(-(gacc[4*gg + 0] + b4.x)));
            gq[4*gg + 1] = __builtin_amdgcn_rcpf(1.f + __expf(-(gacc[4*gg + 1] + b4.y)));
            gq[4*gg + 2] = __builtin_amdgcn_rcpf(1.f + __expf(-(gacc[4*gg + 2] + b4.z)));
            gq[4*gg + 3] = __builtin_amdgcn_rcpf(1.f + __expf(-(gacc[4*gg + 3] + b4.w)));
        }

        if (h) __syncthreads();               // prev head's Ks/Vt readers done

        // ---- scatter K (pairs of consecutive ch) and V (transposed) ----
#pragma unroll
        for (int j = 0; j < 8; ++j) {
            const unsigned pr = (unsigned)f2bf(kacc[2*j])
                              | ((unsigned)f2bf(kacc[2*j+1]) << 16);
            const int off = 8 * (j >> 1) + 4 * lh + 2 * (j & 1);
            *(unsigned*)&Ks[(w * 32 + lc) * KSP + off] = pr;
        }
#pragma unroll
        for (int r = 0; r < 16; ++r)
            Vt[lc * VTP + w * 32 + rowl[r]] = f2bf(vacc[r]);

        const float* tbase = tswz + ((long)(h * 8 + w) * 8) * 1024 + (long)L * 16;
        __syncthreads();

        // ---- t-loop (proven R5 code; qt -> w) ----
        float ls = 0.f;
        f32x16 O = fzero16();
#pragma unroll
        for (int t = 0; t < 8; ++t) {
            bf16x8 kb0 = *(const bf16x8*)&Ks[(t * 32 + lc) * KSP + lh * 8];
            bf16x8 kb1 = *(const bf16x8*)&Ks[(t * 32 + lc) * KSP + 16 + lh * 8];
            f32x16 s = fzero16();
            s = mfma16(kb0, a0, s);
            s = mfma16(kb1, a1, s);

            unsigned pk[8];
            const float* tv = tbase + (long)t * 1024;
#pragma unroll
            for (int gg = 0; gg < 4; ++gg) {
                const float4 tb = *(const float4*)(tv + gg * 4);
                const float4 mb = *(const float4*)&maskb[t * 32 + gg * 8 + 4 * lh];
                const float p0 = exp2_fast(fminf(s[4*gg + 0] + tb.x + mb.x, 43.4f));
                const float p1 = exp2_fast(fminf(s[4*gg + 1] + tb.y + mb.y, 43.4f));
                const float p2 = exp2_fast(fminf(s[4*gg + 2] + tb.z + mb.z, 43.4f));
                const float p3 = exp2_fast(fminf(s[4*gg + 3] + tb.w + mb.w, 43.4f));
                ls += (p0 + p1) + (p2 + p3);
                pk[2*gg]     = (unsigned)f2bf(p0) | ((unsigned)f2bf(p1) << 16);
                pk[2*gg + 1] = (unsigned)f2bf(p2) | ((unsigned)f2bf(p3) << 16);
            }

#pragma unroll
            for (int ss = 0; ss < 2; ++ss) {
                const unsigned give0 = lh ? pk[4*ss]     : pk[4*ss + 2];
                const unsigned give1 = lh ? pk[4*ss + 1] : pk[4*ss + 3];
                const unsigned t0 = __shfl_xor(give0, 32);
                const unsigned t1 = __shfl_xor(give1, 32);
                u32x4 bw;
                bw[0] = lh ? t0 : pk[4*ss];
                bw[1] = lh ? t1 : pk[4*ss + 1];
                bw[2] = lh ? pk[4*ss + 2] : t0;
                bw[3] = lh ? pk[4*ss + 3] : t1;
                const bf16x8 pb = __builtin_bit_cast(bf16x8, bw);
                const bf16x8 va = *(const bf16x8*)&Vt[lc * VTP + t * 32 + ss * 16 + lh * 8];
                O = mfma16(va, pb, O);
            }
        }

        // ---- normalize + gate (g in regs) ----
        ls += __shfl_xor(ls, 32);
        const float rl = __builtin_amdgcn_rcpf(ls);
        unsigned pk2[8];
#pragma unroll
        for (int j = 0; j < 8; ++j) {
            const float o0 = O[2*j]     * rl * gq[2*j];
            const float o1 = O[2*j + 1] * rl * gq[2*j + 1];
            pk2[j] = (unsigned)f2bf(o0) | ((unsigned)f2bf(o1) << 16);
        }

        // ---- out^T += Wo_h^T @ OG_h^T ----
#pragma unroll
        for (int ss = 0; ss < 2; ++ss) {
            const unsigned give0 = lh ? pk2[4*ss]     : pk2[4*ss + 2];
            const unsigned give1 = lh ? pk2[4*ss + 1] : pk2[4*ss + 3];
            const unsigned t0 = __shfl_xor(give0, 32);
            const unsigned t1 = __shfl_xor(give1, 32);
            u32x4 bw;
            bw[0] = lh ? t0 : pk2[4*ss];
            bw[1] = lh ? t1 : pk2[4*ss + 1];
            bw[2] = lh ? pk2[4*ss + 2] : t0;
            bw[3] = lh ? pk2[4*ss + 3] : t1;
            const bf16x8 ogb = __builtin_bit_cast(bf16x8, bw);
#pragma unroll
            for (int ct = 0; ct < 4; ++ct) {
                const bf16x8 wa = *(const bf16x8*)&Wto[(ct * 32 + lc) * 128 + h * 32 + ss * 16 + lh * 8];
                outacc[ct] = mfma16(wa, ogb, outacc[ct]);
            }
        }
    }

    // ---- epilogue: per cout-tile, stage 256 rows through LDS, coalesced ----
#pragma unroll
    for (int ct = 0; ct < 4; ++ct) {
        __syncthreads();
#pragma unroll
        for (int r = 0; r < 16; ++r)
            outs[(w * 32 + lc) * OSP + rowl[r]] = outacc[ct][r];
        __syncthreads();
#pragma unroll
        for (int it = 0; it < 4; ++it) {
            const int fi = it * 512 + tid;    // 0..2047 float4s
            const int row = fi >> 3, c4 = fi & 7;
            const float4 vv = *(const float4*)&outs[row * OSP + c4 * 4];
            const float4 bo4 = *(const float4*)(bo + ct * 32 + c4 * 4);
            float4 st;
            st.x = vv.x + bo4.x; st.y = vv.y + bo4.y;
            st.z = vv.z + bo4.z; st.w = vv.w + bo4.w;
            *(float4*)(out + ((long)i * NJ + row) * NC + ct * 32 + c4 * 4) = st;
        }
    }
}

// ---------------------------------------------------------------------------
extern "C" void kernel_launch(void* const* d_in, const int* in_sizes, int n_in,
                              void* d_out, int out_size, void* d_ws, size_t ws_size,
                              hipStream_t stream) {
    const float* x     = (const float*)d_in[0];
    const float* mask  = (const float*)d_in[1];
    const float* ln_w  = (const float*)d_in[3];
    const float* ln_b  = (const float*)d_in[4];
    const float* w_tri = (const float*)d_in[5];
    const float* wq    = (const float*)d_in[6];
    const float* wk    = (const float*)d_in[7];
    const float* wv    = (const float*)d_in[8];
    const float* wg    = (const float*)d_in[9];
    const float* bg    = (const float*)d_in[10];
    const float* wo    = (const float*)d_in[11];
    const float* bo    = (const float*)d_in[12];
    float* out = (float*)d_out;

    char* p = (char*)d_ws;
    float* tswz = (float*)p; p += (long)NH * NI * NJ * sizeof(float);
    unsigned short* Wt_all   = (unsigned short*)p; p += 4 * 128 * 128 * sizeof(unsigned short);
    unsigned short* Wto      = (unsigned short*)p; p += 128 * 128 * sizeof(unsigned short);
    unsigned short* Wtri_pad = (unsigned short*)p; p += 32 * 128 * sizeof(unsigned short);

    hipLaunchKernelGGL(convert_weights, dim3(336), dim3(256), 0, stream,
                       wq, wk, wv, wg, wo, w_tri, Wt_all, Wto, Wtri_pad);
    hipLaunchKernelGGL(ln_tri, dim3(TOKS / 64), dim3(256), 0, stream,
                       x, ln_w, ln_b, Wtri_pad, tswz);
    hipLaunchKernelGGL(attn_mega, dim3(NI), dim3(512), 0, stream,
                       x, ln_w, ln_b, Wt_all, tswz, mask, Wto, bg, bo, out);
}

// Round 10
// 207.433 us; speedup vs baseline: 1.0095x; 1.0095x over previous
//
#include <hip/hip_runtime.h>
#include <math.h>

// B=1, I=J=256, C=128, H=4, CH=32
#define NI 256
#define NJ 256
#define NC 128
#define NH 4
#define NCH 32
#define TOKS ((long)NI * NJ)

typedef __attribute__((ext_vector_type(8)))  __bf16        bf16x8;
typedef __attribute__((ext_vector_type(8)))  unsigned short u16x8;
typedef __attribute__((ext_vector_type(4)))  unsigned int   u32x4;
typedef __attribute__((ext_vector_type(16))) float         f32x16;

__device__ __forceinline__ unsigned short f2bf(float f) {
    unsigned u = __builtin_bit_cast(unsigned, f);
    u += 0x7fffu + ((u >> 16) & 1u);          // RNE
    return (unsigned short)(u >> 16);
}
__device__ __forceinline__ float bf2f(unsigned short s) {
    return __builtin_bit_cast(float, ((unsigned)s) << 16);
}
__device__ __forceinline__ float exp2_fast(float x) {
    float r;
    asm("v_exp_f32 %0, %1" : "=v"(r) : "v"(x));   // D = 2^S0
    return r;
}
__device__ __forceinline__ f32x16 fzero16() {
    f32x16 z;
#pragma unroll
    for (int r = 0; r < 16; ++r) z[r] = 0.f;
    return z;
}
__device__ __forceinline__ f32x16 mfma16(bf16x8 a, bf16x8 b, f32x16 c) {
    return __builtin_amdgcn_mfma_f32_32x32x16_bf16(a, b, c, 0, 0, 0);
}

#define LOG2E 1.4426950408889634f
#define QSCALE 0.25503486f   // CH^-0.5 * log2e

// ---------------------------------------------------------------------------
// Kernel 0: transpose+convert weights to bf16. w_tri pre-scaled by log2e.
// ---------------------------------------------------------------------------
__global__ __launch_bounds__(256) void convert_weights(
    const float* __restrict__ wq, const float* __restrict__ wk,
    const float* __restrict__ wv, const float* __restrict__ wg,
    const float* __restrict__ wo, const float* __restrict__ w_tri,
    unsigned short* __restrict__ Wt_all, unsigned short* __restrict__ Wto,
    unsigned short* __restrict__ Wtri_pad)
{
    int id = blockIdx.x * 256 + threadIdx.x;          // 0..86015
    if (id < 4 * 16384) {
        int m = id >> 14, r = id & 16383;
        int kk = r >> 7, c = r & 127;
        const float* W = (m == 0) ? wq : (m == 1) ? wk : (m == 2) ? wv : wg;
        Wt_all[(m * 128 + c) * 128 + kk] = f2bf(W[kk * 128 + c]);
    } else if (id < 5 * 16384) {
        int r = id - 4 * 16384;
        int kk = r >> 7, c = r & 127;
        Wto[c * 128 + kk] = f2bf(wo[kk * 128 + c]);
    } else {
        int r = id - 5 * 16384;                        // 0..4095
        int col = r >> 7, kk = r & 127;
        Wtri_pad[col * 128 + kk] = (col < NH) ? f2bf(w_tri[kk * NH + col] * LOG2E)
                                              : (unsigned short)0;
    }
}

// ---------------------------------------------------------------------------
// Kernel 1: LayerNorm + tri bias via MFMA -> tswz (pre-swizzled).
// ---------------------------------------------------------------------------
#define XNP 136
__global__ __launch_bounds__(256, 2) void ln_tri(
    const float* __restrict__ x, const float* __restrict__ ln_w, const float* __restrict__ ln_b,
    const unsigned short* __restrict__ Wtri_pad, float* __restrict__ tswz)
{
    __shared__ unsigned short xn[64 * XNP];   // ~17.4 KB
    const int tid = threadIdx.x;
    const long tok0 = (long)blockIdx.x * 64;

    const int lane8 = tid & 7;
#pragma unroll
    for (int p = 0; p < 2; ++p) {
        const int t = p * 32 + (tid >> 3);
        const float4* xrow = (const float4*)(x + (tok0 + t) * NC + lane8 * 16);
        float4 xv[4];
        float s = 0.f;
#pragma unroll
        for (int u = 0; u < 4; ++u) {
            xv[u] = xrow[u];
            s += xv[u].x + xv[u].y + xv[u].z + xv[u].w;
        }
#pragma unroll
        for (int off = 4; off; off >>= 1) s += __shfl_down(s, off, 8);
        const float mu = __shfl(s, 0, 8) * (1.f / (float)NC);
        float s2 = 0.f;
#pragma unroll
        for (int u = 0; u < 4; ++u) {
            float dx;
            dx = xv[u].x - mu; s2 += dx * dx;
            dx = xv[u].y - mu; s2 += dx * dx;
            dx = xv[u].z - mu; s2 += dx * dx;
            dx = xv[u].w - mu; s2 += dx * dx;
        }
#pragma unroll
        for (int off = 4; off; off >>= 1) s2 += __shfl_down(s2, off, 8);
        const float rstd = rsqrtf(__shfl(s2, 0, 8) * (1.f / (float)NC) + 1e-5f);
#pragma unroll
        for (int u = 0; u < 4; ++u) {
            const int c = lane8 * 16 + u * 4;
            const float4 lw = *(const float4*)(ln_w + c);
            const float4 lb = *(const float4*)(ln_b + c);
            float o0 = (xv[u].x - mu) * rstd * lw.x + lb.x;
            float o1 = (xv[u].y - mu) * rstd * lw.y + lb.y;
            float o2 = (xv[u].z - mu) * rstd * lw.z + lb.z;
            float o3 = (xv[u].w - mu) * rstd * lw.w + lb.w;
            unsigned p0 = (unsigned)f2bf(o0) | ((unsigned)f2bf(o1) << 16);
            unsigned p1 = (unsigned)f2bf(o2) | ((unsigned)f2bf(o3) << 16);
            *(unsigned*)&xn[t * XNP + c]     = p0;
            *(unsigned*)&xn[t * XNP + c + 2] = p1;
        }
    }
    __syncthreads();

    const int L = tid & 63, lh = L >> 5, lc = L & 31;
    f32x16 accT[2];
    accT[0] = fzero16();
    accT[1] = fzero16();

#pragma unroll
    for (int k0 = 0; k0 < 8; ++k0) {
        bf16x8 a0 = *(const bf16x8*)&xn[(lc)      * XNP + k0 * 16 + lh * 8];
        bf16x8 a1 = *(const bf16x8*)&xn[(32 + lc) * XNP + k0 * 16 + lh * 8];
        bf16x8 bt = *(const bf16x8*)&Wtri_pad[lc * 128 + k0 * 16 + lh * 8];
        accT[0] = mfma16(a0, bt, accT[0]);
        accT[1] = mfma16(a1, bt, accT[1]);
    }

    const int a_row = (int)(tok0 >> 8);
    const int b0    = (int)(tok0 & 255);
    if (lc < NH) {
        const int qt_i = a_row >> 5;
        const int lsw  = ((a_row & 31) + 32 * lh) * 16;
#pragma unroll
        for (int mt = 0; mt < 2; ++mt) {
            float* dst = tswz + ((long)((lc * 8 + qt_i) * 8 + (b0 >> 5) + mt)) * 1024 + lsw;
#pragma unroll
            for (int u = 0; u < 4; ++u)
                *(float4*)(dst + u * 4) = make_float4(accT[mt][4*u],   accT[mt][4*u+1],
                                                      accT[mt][4*u+2], accT[mt][4*u+3]);
        }
    }
}

// ---------------------------------------------------------------------------
// Kernel 2: FUSED LayerNorm + projections + attention + gating + out-proj.
// One block per row i: 512 threads = 8 waves; wave w owns token tile w.
// launch_bounds(512, 1): grid=256 on 256 CUs means 1 block/CU is the max
// anyway; min_waves=1 lifts the VGPR cap 128 -> 256 (R8's (512,2) caused
// ~49MB of scratch spills: WRITE_SIZE 81920 vs 32768 logical).
// ---------------------------------------------------------------------------
#define KSP 40    // Ks row stride (shorts)
#define VTP 264   // Vt row stride (shorts)
#define OSP 36    // outs row stride (floats)
__global__ __launch_bounds__(512, 1) void attn_mega(
    const float* __restrict__ x, const float* __restrict__ ln_w, const float* __restrict__ ln_b,
    const unsigned short* __restrict__ Wt_all, const float* __restrict__ tswz,
    const float* __restrict__ mask, const unsigned short* __restrict__ Wto,
    const float* __restrict__ bg, const float* __restrict__ bo,
    float* __restrict__ out)
{
    __shared__ char smem[108032];
    // [0..69632)        : xn [256][136] bf16 (LN result; epilogue reuses as outs)
    unsigned short* xn = (unsigned short*)smem;
    unsigned short* Ks = (unsigned short*)(smem + 69632);    // 256*40*2 = 20480
    unsigned short* Vt = (unsigned short*)(smem + 90112);    // 32*264*2 = 16896
    float*       maskb = (float*)(smem + 107008);            // 1024
    float*        outs = (float*)smem;                       // 256*36*4 = 36864

    const int i = blockIdx.x;
    const int tid = threadIdx.x;                 // 0..511
    const int w = tid >> 6, L = tid & 63, lh = L >> 5, lc = L & 31;

    if (tid < NJ) maskb[tid] = (1.0e9f * LOG2E) * (mask[i * NJ + tid] - 1.0f);

    // ---- LayerNorm the row's 256 tokens into LDS (8 lanes per token) ----
    const int lane8 = tid & 7;
#pragma unroll
    for (int p = 0; p < 4; ++p) {
        const int t = p * 64 + (tid >> 3);
        const float4* xrow = (const float4*)(x + ((long)i * NJ + t) * NC + lane8 * 16);
        float4 xv[4];
        float s = 0.f;
#pragma unroll
        for (int u = 0; u < 4; ++u) {
            xv[u] = xrow[u];
            s += xv[u].x + xv[u].y + xv[u].z + xv[u].w;
        }
#pragma unroll
        for (int off = 4; off; off >>= 1) s += __shfl_down(s, off, 8);
        const float mu = __shfl(s, 0, 8) * (1.f / (float)NC);
        float s2 = 0.f;
#pragma unroll
        for (int u = 0; u < 4; ++u) {
            float dx;
            dx = xv[u].x - mu; s2 += dx * dx;
            dx = xv[u].y - mu; s2 += dx * dx;
            dx = xv[u].z - mu; s2 += dx * dx;
            dx = xv[u].w - mu; s2 += dx * dx;
        }
#pragma unroll
        for (int off = 4; off; off >>= 1) s2 += __shfl_down(s2, off, 8);
        const float rstd = rsqrtf(__shfl(s2, 0, 8) * (1.f / (float)NC) + 1e-5f);
#pragma unroll
        for (int u = 0; u < 4; ++u) {
            const int c = lane8 * 16 + u * 4;
            const float4 lw = *(const float4*)(ln_w + c);
            const float4 lb = *(const float4*)(ln_b + c);
            float o0 = (xv[u].x - mu) * rstd * lw.x + lb.x;
            float o1 = (xv[u].y - mu) * rstd * lw.y + lb.y;
            float o2 = (xv[u].z - mu) * rstd * lw.z + lb.z;
            float o3 = (xv[u].w - mu) * rstd * lw.w + lb.w;
            unsigned p0 = (unsigned)f2bf(o0) | ((unsigned)f2bf(o1) << 16);
            unsigned p1 = (unsigned)f2bf(o2) | ((unsigned)f2bf(o3) << 16);
            *(unsigned*)&xn[t * XNP + c]     = p0;
            *(unsigned*)&xn[t * XNP + c + 2] = p1;
        }
    }
    __syncthreads();

    int rowl[16];
#pragma unroll
    for (int r = 0; r < 16; ++r) rowl[r] = (r & 3) + 8 * (r >> 2) + 4 * lh;

    f32x16 outacc[4];
#pragma unroll
    for (int ct = 0; ct < 4; ++ct) outacc[ct] = fzero16();

#pragma unroll
    for (int h = 0; h < NH; ++h) {
        // ---- per-head projections (registers only) ----
        f32x16 qacc = fzero16(), kacc = fzero16(), vacc = fzero16(), gacc = fzero16();
        const unsigned short* Wq = Wt_all + ((0 * 128 + h * 32 + lc) * 128);
        const unsigned short* Wk = Wt_all + ((1 * 128 + h * 32 + lc) * 128);
        const unsigned short* Wv = Wt_all + ((2 * 128 + h * 32 + lc) * 128);
        const unsigned short* Wg = Wt_all + ((3 * 128 + h * 32 + lc) * 128);
        const unsigned short* xnrow = xn + (w * 32 + lc) * XNP;
#pragma unroll
        for (int k0 = 0; k0 < 8; ++k0) {
            const int ko = k0 * 16 + lh * 8;
            const bf16x8 xf  = *(const bf16x8*)&xnrow[ko];
            const bf16x8 wqf = *(const bf16x8*)&Wq[ko];
            const bf16x8 wkf = *(const bf16x8*)&Wk[ko];
            const bf16x8 wvf = *(const bf16x8*)&Wv[ko];
            const bf16x8 wgf = *(const bf16x8*)&Wg[ko];
            qacc = mfma16(wqf, xf, qacc);     // swapped: C[reg=ch][lane=token]
            kacc = mfma16(wkf, xf, kacc);     // swapped
            vacc = mfma16(xf, wvf, vacc);     // normal:  C[reg=token][lane=ch]
            gacc = mfma16(wgf, xf, gacc);     // swapped
        }

        // q: scale + pack pairs, assemble B-frags in-register (lane^32 idiom)
        unsigned pkq[8];
#pragma unroll
        for (int j = 0; j < 8; ++j)
            pkq[j] = (unsigned)f2bf(qacc[2*j] * QSCALE)
                   | ((unsigned)f2bf(qacc[2*j+1] * QSCALE) << 16);
        bf16x8 a0, a1;
#pragma unroll
        for (int ss = 0; ss < 2; ++ss) {
            const unsigned give0 = lh ? pkq[4*ss]     : pkq[4*ss + 2];
            const unsigned give1 = lh ? pkq[4*ss + 1] : pkq[4*ss + 3];
            const unsigned t0 = __shfl_xor(give0, 32);
            const unsigned t1 = __shfl_xor(give1, 32);
            u32x4 bw;
            bw[0] = lh ? t0 : pkq[4*ss];
            bw[1] = lh ? t1 : pkq[4*ss + 1];
            bw[2] = lh ? pkq[4*ss + 2] : t0;
            bw[3] = lh ? pkq[4*ss + 3] : t1;
            if (ss == 0) a0 = __builtin_bit_cast(bf16x8, bw);
            else         a1 = __builtin_bit_cast(bf16x8, bw);
        }

        // g: sigmoid in f32 regs (reg r <-> ch rowl(r), matches O layout)
        float gq[16];
#pragma unroll
        for (int gg = 0; gg < 4; ++gg) {
            const float4 b4 = *(const float4*)(bg + h * 32 + gg * 8 + 4 * lh);
            gq[4*gg + 0] = __builtin_amdgcn_rcpf(1.f + __expf(-(gacc[4*gg + 0] + b4.x)));
            gq[4*gg + 1] = __builtin_amdgcn_rcpf(1.f + __expf(-(gacc[4*gg + 1] + b4.y)));
            gq[4*gg + 2] = __builtin_amdgcn_rcpf(1.f + __expf(-(gacc[4*gg + 2] + b4.z)));
            gq[4*gg + 3] = __builtin_amdgcn_rcpf(1.f + __expf(-(gacc[4*gg + 3] + b4.w)));
        }

        if (h) __syncthreads();               // prev head's Ks/Vt readers done

        // ---- scatter K (pairs of consecutive ch) and V (transposed) ----
#pragma unroll
        for (int j = 0; j < 8; ++j) {
            const unsigned pr = (unsigned)f2bf(kacc[2*j])
                              | ((unsigned)f2bf(kacc[2*j+1]) << 16);
            const int off = 8 * (j >> 1) + 4 * lh + 2 * (j & 1);
            *(unsigned*)&Ks[(w * 32 + lc) * KSP + off] = pr;
        }
#pragma unroll
        for (int r = 0; r < 16; ++r)
            Vt[lc * VTP + w * 32 + rowl[r]] = f2bf(vacc[r]);

        const float* tbase = tswz + ((long)(h * 8 + w) * 8) * 1024 + (long)L * 16;
        __syncthreads();

        // ---- t-loop (proven R5 code; qt -> w) ----
        float ls = 0.f;
        f32x16 O = fzero16();
#pragma unroll
        for (int t = 0; t < 8; ++t) {
            bf16x8 kb0 = *(const bf16x8*)&Ks[(t * 32 + lc) * KSP + lh * 8];
            bf16x8 kb1 = *(const bf16x8*)&Ks[(t * 32 + lc) * KSP + 16 + lh * 8];
            f32x16 s = fzero16();
            s = mfma16(kb0, a0, s);
            s = mfma16(kb1, a1, s);

            unsigned pk[8];
            const float* tv = tbase + (long)t * 1024;
#pragma unroll
            for (int gg = 0; gg < 4; ++gg) {
                const float4 tb = *(const float4*)(tv + gg * 4);
                const float4 mb = *(const float4*)&maskb[t * 32 + gg * 8 + 4 * lh];
                const float p0 = exp2_fast(fminf(s[4*gg + 0] + tb.x + mb.x, 43.4f));
                const float p1 = exp2_fast(fminf(s[4*gg + 1] + tb.y + mb.y, 43.4f));
                const float p2 = exp2_fast(fminf(s[4*gg + 2] + tb.z + mb.z, 43.4f));
                const float p3 = exp2_fast(fminf(s[4*gg + 3] + tb.w + mb.w, 43.4f));
                ls += (p0 + p1) + (p2 + p3);
                pk[2*gg]     = (unsigned)f2bf(p0) | ((unsigned)f2bf(p1) << 16);
                pk[2*gg + 1] = (unsigned)f2bf(p2) | ((unsigned)f2bf(p3) << 16);
            }

#pragma unroll
            for (int ss = 0; ss < 2; ++ss) {
                const unsigned give0 = lh ? pk[4*ss]     : pk[4*ss + 2];
                const unsigned give1 = lh ? pk[4*ss + 1] : pk[4*ss + 3];
                const unsigned t0 = __shfl_xor(give0, 32);
                const unsigned t1 = __shfl_xor(give1, 32);
                u32x4 bw;
                bw[0] = lh ? t0 : pk[4*ss];
                bw[1] = lh ? t1 : pk[4*ss + 1];
                bw[2] = lh ? pk[4*ss + 2] : t0;
                bw[3] = lh ? pk[4*ss + 3] : t1;
                const bf16x8 pb = __builtin_bit_cast(bf16x8, bw);
                const bf16x8 va = *(const bf16x8*)&Vt[lc * VTP + t * 32 + ss * 16 + lh * 8];
                O = mfma16(va, pb, O);
            }
        }

        // ---- normalize + gate (g in regs) ----
        ls += __shfl_xor(ls, 32);
        const float rl = __builtin_amdgcn_rcpf(ls);
        unsigned pk2[8];
#pragma unroll
        for (int j = 0; j < 8; ++j) {
            const float o0 = O[2*j]     * rl * gq[2*j];
            const float o1 = O[2*j + 1] * rl * gq[2*j + 1];
            pk2[j] = (unsigned)f2bf(o0) | ((unsigned)f2bf(o1) << 16);
        }

        // ---- out^T += Wo_h^T @ OG_h^T ----
#pragma unroll
        for (int ss = 0; ss < 2; ++ss) {
            const unsigned give0 = lh ? pk2[4*ss]     : pk2[4*ss + 2];
            const unsigned give1 = lh ? pk2[4*ss + 1] : pk2[4*ss + 3];
            const unsigned t0 = __shfl_xor(give0, 32);
            const unsigned t1 = __shfl_xor(give1, 32);
            u32x4 bw;
            bw[0] = lh ? t0 : pk2[4*ss];
            bw[1] = lh ? t1 : pk2[4*ss + 1];
            bw[2] = lh ? pk2[4*ss + 2] : t0;
            bw[3] = lh ? pk2[4*ss + 3] : t1;
            const bf16x8 ogb = __builtin_bit_cast(bf16x8, bw);
#pragma unroll
            for (int ct = 0; ct < 4; ++ct) {
                const bf16x8 wa = *(const bf16x8*)&Wto[(ct * 32 + lc) * 128 + h * 32 + ss * 16 + lh * 8];
                outacc[ct] = mfma16(wa, ogb, outacc[ct]);
            }
        }
    }

    // ---- epilogue: per cout-tile, stage 256 rows through LDS, coalesced ----
#pragma unroll
    for (int ct = 0; ct < 4; ++ct) {
        __syncthreads();
#pragma unroll
        for (int r = 0; r < 16; ++r)
            outs[(w * 32 + lc) * OSP + rowl[r]] = outacc[ct][r];
        __syncthreads();
#pragma unroll
        for (int it = 0; it < 4; ++it) {
            const int fi = it * 512 + tid;    // 0..2047 float4s
            const int row = fi >> 3, c4 = fi & 7;
            const float4 vv = *(const float4*)&outs[row * OSP + c4 * 4];
            const float4 bo4 = *(const float4*)(bo + ct * 32 + c4 * 4);
            float4 st;
            st.x = vv.x + bo4.x; st.y = vv.y + bo4.y;
            st.z = vv.z + bo4.z; st.w = vv.w + bo4.w;
            *(float4*)(out + ((long)i * NJ + row) * NC + ct * 32 + c4 * 4) = st;
        }
    }
}

// ---------------------------------------------------------------------------
extern "C" void kernel_launch(void* const* d_in, const int* in_sizes, int n_in,
                              void* d_out, int out_size, void* d_ws, size_t ws_size,
                              hipStream_t stream) {
    const float* x     = (const float*)d_in[0];
    const float* mask  = (const float*)d_in[1];
    const float* ln_w  = (const float*)d_in[3];
    const float* ln_b  = (const float*)d_in[4];
    const float* w_tri = (const float*)d_in[5];
    const float* wq    = (const float*)d_in[6];
    const float* wk    = (const float*)d_in[7];
    const float* wv    = (const float*)d_in[8];
    const float* wg    = (const float*)d_in[9];
    const float* bg    = (const float*)d_in[10];
    const float* wo    = (const float*)d_in[11];
    const float* bo    = (const float*)d_in[12];
    float* out = (float*)d_out;

    char* p = (char*)d_ws;
    float* tswz = (float*)p; p += (long)NH * NI * NJ * sizeof(float);
    unsigned short* Wt_all   = (unsigned short*)p; p += 4 * 128 * 128 * sizeof(unsigned short);
    unsigned short* Wto      = (unsigned short*)p; p += 128 * 128 * sizeof(unsigned short);
    unsigned short* Wtri_pad = (unsigned short*)p; p += 32 * 128 * sizeof(unsigned short);

    hipLaunchKernelGGL(convert_weights, dim3(336), dim3(256), 0, stream,
                       wq, wk, wv, wg, wo, w_tri, Wt_all, Wto, Wtri_pad);
    hipLaunchKernelGGL(ln_tri, dim3(TOKS / 64), dim3(256), 0, stream,
                       x, ln_w, ln_b, Wtri_pad, tswz);
    hipLaunchKernelGGL(attn_mega, dim3(NI), dim3(512), 0, stream,
                       x, ln_w, ln_b, Wt_all, tswz, mask, Wto, bg, bo, out);
}

// Round 11
// 180.086 us; speedup vs baseline: 1.1628x; 1.1519x over previous
//
#include <hip/hip_runtime.h>
#include <math.h>

// B=1, I=J=256, C=128, H=4, CH=32
#define NI 256
#define NJ 256
#define NC 128
#define NH 4
#define NCH 32
#define TOKS ((long)NI * NJ)

typedef __attribute__((ext_vector_type(8)))  __bf16        bf16x8;
typedef __attribute__((ext_vector_type(8)))  unsigned short u16x8;
typedef __attribute__((ext_vector_type(4)))  unsigned int   u32x4;
typedef __attribute__((ext_vector_type(16))) float         f32x16;

__device__ __forceinline__ unsigned short f2bf(float f) {
    unsigned u = __builtin_bit_cast(unsigned, f);
    u += 0x7fffu + ((u >> 16) & 1u);          // RNE
    return (unsigned short)(u >> 16);
}
__device__ __forceinline__ float bf2f(unsigned short s) {
    return __builtin_bit_cast(float, ((unsigned)s) << 16);
}
__device__ __forceinline__ float exp2_fast(float x) {
    float r;
    asm("v_exp_f32 %0, %1" : "=v"(r) : "v"(x));   // D = 2^S0
    return r;
}
__device__ __forceinline__ f32x16 fzero16() {
    f32x16 z;
#pragma unroll
    for (int r = 0; r < 16; ++r) z[r] = 0.f;
    return z;
}
__device__ __forceinline__ f32x16 mfma16(bf16x8 a, bf16x8 b, f32x16 c) {
    return __builtin_amdgcn_mfma_f32_32x32x16_bf16(a, b, c, 0, 0, 0);
}

#define LOG2E 1.4426950408889634f
#define QSCALE 0.25503486f   // CH^-0.5 * log2e

// ---------------------------------------------------------------------------
// Kernel 0: transpose+convert weights to bf16. w_tri pre-scaled by log2e.
// ---------------------------------------------------------------------------
__global__ __launch_bounds__(256) void convert_weights(
    const float* __restrict__ wq, const float* __restrict__ wk,
    const float* __restrict__ wv, const float* __restrict__ wg,
    const float* __restrict__ wo, const float* __restrict__ w_tri,
    unsigned short* __restrict__ Wt_all, unsigned short* __restrict__ Wto,
    unsigned short* __restrict__ Wtri_pad)
{
    int id = blockIdx.x * 256 + threadIdx.x;          // 0..86015
    if (id < 4 * 16384) {
        int m = id >> 14, r = id & 16383;
        int kk = r >> 7, c = r & 127;
        const float* W = (m == 0) ? wq : (m == 1) ? wk : (m == 2) ? wv : wg;
        Wt_all[(m * 128 + c) * 128 + kk] = f2bf(W[kk * 128 + c]);
    } else if (id < 5 * 16384) {
        int r = id - 4 * 16384;
        int kk = r >> 7, c = r & 127;
        Wto[c * 128 + kk] = f2bf(wo[kk * 128 + c]);
    } else {
        int r = id - 5 * 16384;                        // 0..4095
        int col = r >> 7, kk = r & 127;
        Wtri_pad[col * 128 + kk] = (col < NH) ? f2bf(w_tri[kk * NH + col] * LOG2E)
                                              : (unsigned short)0;
    }
}

// ---------------------------------------------------------------------------
// Kernel 1: LayerNorm + tri bias via MFMA -> tswz (pre-swizzled).
// ---------------------------------------------------------------------------
#define XNP 136
__global__ __launch_bounds__(256, 2) void ln_tri(
    const float* __restrict__ x, const float* __restrict__ ln_w, const float* __restrict__ ln_b,
    const unsigned short* __restrict__ Wtri_pad, float* __restrict__ tswz)
{
    __shared__ unsigned short xn[64 * XNP];   // ~17.4 KB
    const int tid = threadIdx.x;
    const long tok0 = (long)blockIdx.x * 64;

    const int lane8 = tid & 7;
#pragma unroll
    for (int p = 0; p < 2; ++p) {
        const int t = p * 32 + (tid >> 3);
        const float4* xrow = (const float4*)(x + (tok0 + t) * NC + lane8 * 16);
        float4 xv[4];
        float s = 0.f;
#pragma unroll
        for (int u = 0; u < 4; ++u) {
            xv[u] = xrow[u];
            s += xv[u].x + xv[u].y + xv[u].z + xv[u].w;
        }
#pragma unroll
        for (int off = 4; off; off >>= 1) s += __shfl_down(s, off, 8);
        const float mu = __shfl(s, 0, 8) * (1.f / (float)NC);
        float s2 = 0.f;
#pragma unroll
        for (int u = 0; u < 4; ++u) {
            float dx;
            dx = xv[u].x - mu; s2 += dx * dx;
            dx = xv[u].y - mu; s2 += dx * dx;
            dx = xv[u].z - mu; s2 += dx * dx;
            dx = xv[u].w - mu; s2 += dx * dx;
        }
#pragma unroll
        for (int off = 4; off; off >>= 1) s2 += __shfl_down(s2, off, 8);
        const float rstd = rsqrtf(__shfl(s2, 0, 8) * (1.f / (float)NC) + 1e-5f);
#pragma unroll
        for (int u = 0; u < 4; ++u) {
            const int c = lane8 * 16 + u * 4;
            const float4 lw = *(const float4*)(ln_w + c);
            const float4 lb = *(const float4*)(ln_b + c);
            float o0 = (xv[u].x - mu) * rstd * lw.x + lb.x;
            float o1 = (xv[u].y - mu) * rstd * lw.y + lb.y;
            float o2 = (xv[u].z - mu) * rstd * lw.z + lb.z;
            float o3 = (xv[u].w - mu) * rstd * lw.w + lb.w;
            unsigned p0 = (unsigned)f2bf(o0) | ((unsigned)f2bf(o1) << 16);
            unsigned p1 = (unsigned)f2bf(o2) | ((unsigned)f2bf(o3) << 16);
            *(unsigned*)&xn[t * XNP + c]     = p0;
            *(unsigned*)&xn[t * XNP + c + 2] = p1;
        }
    }
    __syncthreads();

    const int L = tid & 63, lh = L >> 5, lc = L & 31;
    f32x16 accT[2];
    accT[0] = fzero16();
    accT[1] = fzero16();

#pragma unroll
    for (int k0 = 0; k0 < 8; ++k0) {
        bf16x8 a0 = *(const bf16x8*)&xn[(lc)      * XNP + k0 * 16 + lh * 8];
        bf16x8 a1 = *(const bf16x8*)&xn[(32 + lc) * XNP + k0 * 16 + lh * 8];
        bf16x8 bt = *(const bf16x8*)&Wtri_pad[lc * 128 + k0 * 16 + lh * 8];
        accT[0] = mfma16(a0, bt, accT[0]);
        accT[1] = mfma16(a1, bt, accT[1]);
    }

    const int a_row = (int)(tok0 >> 8);
    const int b0    = (int)(tok0 & 255);
    if (lc < NH) {
        const int qt_i = a_row >> 5;
        const int lsw  = ((a_row & 31) + 32 * lh) * 16;
#pragma unroll
        for (int mt = 0; mt < 2; ++mt) {
            float* dst = tswz + ((long)((lc * 8 + qt_i) * 8 + (b0 >> 5) + mt)) * 1024 + lsw;
#pragma unroll
            for (int u = 0; u < 4; ++u)
                *(float4*)(dst + u * 4) = make_float4(accT[mt][4*u],   accT[mt][4*u+1],
                                                      accT[mt][4*u+2], accT[mt][4*u+3]);
        }
    }
}

// ---------------------------------------------------------------------------
// Kernel 2: FUSED LayerNorm + projections + attention + gating + out-proj.
// v3: register-pressure reduction (R8/R10 spilled ~48MB at VGPR=128):
//   - h-loop NOT unrolled (kills 4x cross-head live-range hoisting)
//   - two-pass projection: k+v computed+scattered first (accs die), then q+g
//   - gate packed to bf16 pairs (8 regs, R5 numerics) instead of 16 f32
// ---------------------------------------------------------------------------
#define KSP 40    // Ks row stride (shorts)
#define VTP 264   // Vt row stride (shorts)
#define OSP 36    // outs row stride (floats)
__global__ __launch_bounds__(512, 1) void attn_mega(
    const float* __restrict__ x, const float* __restrict__ ln_w, const float* __restrict__ ln_b,
    const unsigned short* __restrict__ Wt_all, const float* __restrict__ tswz,
    const float* __restrict__ mask, const unsigned short* __restrict__ Wto,
    const float* __restrict__ bg, const float* __restrict__ bo,
    float* __restrict__ out)
{
    __shared__ char smem[108032];
    // [0..69632)        : xn [256][136] bf16 (LN result; epilogue reuses as outs)
    unsigned short* xn = (unsigned short*)smem;
    unsigned short* Ks = (unsigned short*)(smem + 69632);    // 256*40*2 = 20480
    unsigned short* Vt = (unsigned short*)(smem + 90112);    // 32*264*2 = 16896
    float*       maskb = (float*)(smem + 107008);            // 1024
    float*        outs = (float*)smem;                       // 256*36*4 = 36864

    const int i = blockIdx.x;
    const int tid = threadIdx.x;                 // 0..511
    const int w = tid >> 6, L = tid & 63, lh = L >> 5, lc = L & 31;

    if (tid < NJ) maskb[tid] = (1.0e9f * LOG2E) * (mask[i * NJ + tid] - 1.0f);

    // ---- LayerNorm the row's 256 tokens into LDS (8 lanes per token) ----
    const int lane8 = tid & 7;
#pragma unroll
    for (int p = 0; p < 4; ++p) {
        const int t = p * 64 + (tid >> 3);
        const float4* xrow = (const float4*)(x + ((long)i * NJ + t) * NC + lane8 * 16);
        float4 xv[4];
        float s = 0.f;
#pragma unroll
        for (int u = 0; u < 4; ++u) {
            xv[u] = xrow[u];
            s += xv[u].x + xv[u].y + xv[u].z + xv[u].w;
        }
#pragma unroll
        for (int off = 4; off; off >>= 1) s += __shfl_down(s, off, 8);
        const float mu = __shfl(s, 0, 8) * (1.f / (float)NC);
        float s2 = 0.f;
#pragma unroll
        for (int u = 0; u < 4; ++u) {
            float dx;
            dx = xv[u].x - mu; s2 += dx * dx;
            dx = xv[u].y - mu; s2 += dx * dx;
            dx = xv[u].z - mu; s2 += dx * dx;
            dx = xv[u].w - mu; s2 += dx * dx;
        }
#pragma unroll
        for (int off = 4; off; off >>= 1) s2 += __shfl_down(s2, off, 8);
        const float rstd = rsqrtf(__shfl(s2, 0, 8) * (1.f / (float)NC) + 1e-5f);
#pragma unroll
        for (int u = 0; u < 4; ++u) {
            const int c = lane8 * 16 + u * 4;
            const float4 lw = *(const float4*)(ln_w + c);
            const float4 lb = *(const float4*)(ln_b + c);
            float o0 = (xv[u].x - mu) * rstd * lw.x + lb.x;
            float o1 = (xv[u].y - mu) * rstd * lw.y + lb.y;
            float o2 = (xv[u].z - mu) * rstd * lw.z + lb.z;
            float o3 = (xv[u].w - mu) * rstd * lw.w + lb.w;
            unsigned p0 = (unsigned)f2bf(o0) | ((unsigned)f2bf(o1) << 16);
            unsigned p1 = (unsigned)f2bf(o2) | ((unsigned)f2bf(o3) << 16);
            *(unsigned*)&xn[t * XNP + c]     = p0;
            *(unsigned*)&xn[t * XNP + c + 2] = p1;
        }
    }
    __syncthreads();

    int rowl[16];
#pragma unroll
    for (int r = 0; r < 16; ++r) rowl[r] = (r & 3) + 8 * (r >> 2) + 4 * lh;

    f32x16 outacc[4];
#pragma unroll
    for (int ct = 0; ct < 4; ++ct) outacc[ct] = fzero16();

#pragma unroll 1
    for (int h = 0; h < NH; ++h) {
        const unsigned short* xnrow = xn + (w * 32 + lc) * XNP;

        // ---- pass 1: k + v projections (accs die at scatter) ----
        {
            f32x16 kacc = fzero16(), vacc = fzero16();
            const unsigned short* Wk = Wt_all + ((1 * 128 + h * 32 + lc) * 128);
            const unsigned short* Wv = Wt_all + ((2 * 128 + h * 32 + lc) * 128);
#pragma unroll
            for (int k0 = 0; k0 < 8; ++k0) {
                const int ko = k0 * 16 + lh * 8;
                const bf16x8 xf = *(const bf16x8*)&xnrow[ko];
                kacc = mfma16(*(const bf16x8*)&Wk[ko], xf, kacc);  // C[reg=ch][lane=token]
                vacc = mfma16(xf, *(const bf16x8*)&Wv[ko], vacc);  // C[reg=token][lane=ch]
            }
            if (h) __syncthreads();           // prev head's Ks/Vt readers done
#pragma unroll
            for (int j = 0; j < 8; ++j) {
                const unsigned pr = (unsigned)f2bf(kacc[2*j])
                                  | ((unsigned)f2bf(kacc[2*j+1]) << 16);
                const int off = 8 * (j >> 1) + 4 * lh + 2 * (j & 1);
                *(unsigned*)&Ks[(w * 32 + lc) * KSP + off] = pr;
            }
#pragma unroll
            for (int r = 0; r < 16; ++r)
                Vt[lc * VTP + w * 32 + rowl[r]] = f2bf(vacc[r]);
        }

        // ---- pass 2: q + g projections ----
        bf16x8 a0, a1;
        unsigned gp[8];                       // gate, packed bf16 pairs
        {
            f32x16 qacc = fzero16(), gacc = fzero16();
            const unsigned short* Wq = Wt_all + ((0 * 128 + h * 32 + lc) * 128);
            const unsigned short* Wg = Wt_all + ((3 * 128 + h * 32 + lc) * 128);
#pragma unroll
            for (int k0 = 0; k0 < 8; ++k0) {
                const int ko = k0 * 16 + lh * 8;
                const bf16x8 xf = *(const bf16x8*)&xnrow[ko];
                qacc = mfma16(*(const bf16x8*)&Wq[ko], xf, qacc);  // swapped
                gacc = mfma16(*(const bf16x8*)&Wg[ko], xf, gacc);  // swapped
            }
            unsigned pkq[8];
#pragma unroll
            for (int j = 0; j < 8; ++j)
                pkq[j] = (unsigned)f2bf(qacc[2*j] * QSCALE)
                       | ((unsigned)f2bf(qacc[2*j+1] * QSCALE) << 16);
#pragma unroll
            for (int ss = 0; ss < 2; ++ss) {
                const unsigned give0 = lh ? pkq[4*ss]     : pkq[4*ss + 2];
                const unsigned give1 = lh ? pkq[4*ss + 1] : pkq[4*ss + 3];
                const unsigned t0 = __shfl_xor(give0, 32);
                const unsigned t1 = __shfl_xor(give1, 32);
                u32x4 bw;
                bw[0] = lh ? t0 : pkq[4*ss];
                bw[1] = lh ? t1 : pkq[4*ss + 1];
                bw[2] = lh ? pkq[4*ss + 2] : t0;
                bw[3] = lh ? pkq[4*ss + 3] : t1;
                if (ss == 0) a0 = __builtin_bit_cast(bf16x8, bw);
                else         a1 = __builtin_bit_cast(bf16x8, bw);
            }
#pragma unroll
            for (int gg = 0; gg < 4; ++gg) {
                const float4 b4 = *(const float4*)(bg + h * 32 + gg * 8 + 4 * lh);
                const float g0 = __builtin_amdgcn_rcpf(1.f + __expf(-(gacc[4*gg + 0] + b4.x)));
                const float g1 = __builtin_amdgcn_rcpf(1.f + __expf(-(gacc[4*gg + 1] + b4.y)));
                const float g2 = __builtin_amdgcn_rcpf(1.f + __expf(-(gacc[4*gg + 2] + b4.z)));
                const float g3 = __builtin_amdgcn_rcpf(1.f + __expf(-(gacc[4*gg + 3] + b4.w)));
                gp[2*gg]     = (unsigned)f2bf(g0) | ((unsigned)f2bf(g1) << 16);
                gp[2*gg + 1] = (unsigned)f2bf(g2) | ((unsigned)f2bf(g3) << 16);
            }
        }

        const float* tbase = tswz + ((long)(h * 8 + w) * 8) * 1024 + (long)L * 16;
        __syncthreads();                      // Ks/Vt staged

        // ---- t-loop (proven R5 code; qt -> w) ----
        float ls = 0.f;
        f32x16 O = fzero16();
#pragma unroll
        for (int t = 0; t < 8; ++t) {
            bf16x8 kb0 = *(const bf16x8*)&Ks[(t * 32 + lc) * KSP + lh * 8];
            bf16x8 kb1 = *(const bf16x8*)&Ks[(t * 32 + lc) * KSP + 16 + lh * 8];
            f32x16 s = fzero16();
            s = mfma16(kb0, a0, s);
            s = mfma16(kb1, a1, s);

            unsigned pk[8];
            const float* tv = tbase + (long)t * 1024;
#pragma unroll
            for (int gg = 0; gg < 4; ++gg) {
                const float4 tb = *(const float4*)(tv + gg * 4);
                const float4 mb = *(const float4*)&maskb[t * 32 + gg * 8 + 4 * lh];
                const float p0 = exp2_fast(fminf(s[4*gg + 0] + tb.x + mb.x, 43.4f));
                const float p1 = exp2_fast(fminf(s[4*gg + 1] + tb.y + mb.y, 43.4f));
                const float p2 = exp2_fast(fminf(s[4*gg + 2] + tb.z + mb.z, 43.4f));
                const float p3 = exp2_fast(fminf(s[4*gg + 3] + tb.w + mb.w, 43.4f));
                ls += (p0 + p1) + (p2 + p3);
                pk[2*gg]     = (unsigned)f2bf(p0) | ((unsigned)f2bf(p1) << 16);
                pk[2*gg + 1] = (unsigned)f2bf(p2) | ((unsigned)f2bf(p3) << 16);
            }

#pragma unroll
            for (int ss = 0; ss < 2; ++ss) {
                const unsigned give0 = lh ? pk[4*ss]     : pk[4*ss + 2];
                const unsigned give1 = lh ? pk[4*ss + 1] : pk[4*ss + 3];
                const unsigned t0 = __shfl_xor(give0, 32);
                const unsigned t1 = __shfl_xor(give1, 32);
                u32x4 bw;
                bw[0] = lh ? t0 : pk[4*ss];
                bw[1] = lh ? t1 : pk[4*ss + 1];
                bw[2] = lh ? pk[4*ss + 2] : t0;
                bw[3] = lh ? pk[4*ss + 3] : t1;
                const bf16x8 pb = __builtin_bit_cast(bf16x8, bw);
                const bf16x8 va = *(const bf16x8*)&Vt[lc * VTP + t * 32 + ss * 16 + lh * 8];
                O = mfma16(va, pb, O);
            }
        }

        // ---- normalize + gate (packed bf16 gate, R5 numerics) ----
        ls += __shfl_xor(ls, 32);
        const float rl = __builtin_amdgcn_rcpf(ls);
        unsigned pk2[8];
#pragma unroll
        for (int j = 0; j < 8; ++j) {
            const float o0 = O[2*j]     * rl * bf2f((unsigned short)(gp[j] & 0xffffu));
            const float o1 = O[2*j + 1] * rl * bf2f((unsigned short)(gp[j] >> 16));
            pk2[j] = (unsigned)f2bf(o0) | ((unsigned)f2bf(o1) << 16);
        }

        // ---- out^T += Wo_h^T @ OG_h^T ----
#pragma unroll
        for (int ss = 0; ss < 2; ++ss) {
            const unsigned give0 = lh ? pk2[4*ss]     : pk2[4*ss + 2];
            const unsigned give1 = lh ? pk2[4*ss + 1] : pk2[4*ss + 3];
            const unsigned t0 = __shfl_xor(give0, 32);
            const unsigned t1 = __shfl_xor(give1, 32);
            u32x4 bw;
            bw[0] = lh ? t0 : pk2[4*ss];
            bw[1] = lh ? t1 : pk2[4*ss + 1];
            bw[2] = lh ? pk2[4*ss + 2] : t0;
            bw[3] = lh ? pk2[4*ss + 3] : t1;
            const bf16x8 ogb = __builtin_bit_cast(bf16x8, bw);
#pragma unroll
            for (int ct = 0; ct < 4; ++ct) {
                const bf16x8 wa = *(const bf16x8*)&Wto[(ct * 32 + lc) * 128 + h * 32 + ss * 16 + lh * 8];
                outacc[ct] = mfma16(wa, ogb, outacc[ct]);
            }
        }
    }

    // ---- epilogue: per cout-tile, stage 256 rows through LDS, coalesced ----
#pragma unroll
    for (int ct = 0; ct < 4; ++ct) {
        __syncthreads();
#pragma unroll
        for (int r = 0; r < 16; ++r)
            outs[(w * 32 + lc) * OSP + rowl[r]] = outacc[ct][r];
        __syncthreads();
#pragma unroll
        for (int it = 0; it < 4; ++it) {
            const int fi = it * 512 + tid;    // 0..2047 float4s
            const int row = fi >> 3, c4 = fi & 7;
            const float4 vv = *(const float4*)&outs[row * OSP + c4 * 4];
            const float4 bo4 = *(const float4*)(bo + ct * 32 + c4 * 4);
            float4 st;
            st.x = vv.x + bo4.x; st.y = vv.y + bo4.y;
            st.z = vv.z + bo4.z; st.w = vv.w + bo4.w;
            *(float4*)(out + ((long)i * NJ + row) * NC + ct * 32 + c4 * 4) = st;
        }
    }
}

// ---------------------------------------------------------------------------
extern "C" void kernel_launch(void* const* d_in, const int* in_sizes, int n_in,
                              void* d_out, int out_size, void* d_ws, size_t ws_size,
                              hipStream_t stream) {
    const float* x     = (const float*)d_in[0];
    const float* mask  = (const float*)d_in[1];
    const float* ln_w  = (const float*)d_in[3];
    const float* ln_b  = (const float*)d_in[4];
    const float* w_tri = (const float*)d_in[5];
    const float* wq    = (const float*)d_in[6];
    const float* wk    = (const float*)d_in[7];
    const float* wv    = (const float*)d_in[8];
    const float* wg    = (const float*)d_in[9];
    const float* bg    = (const float*)d_in[10];
    const float* wo    = (const float*)d_in[11];
    const float* bo    = (const float*)d_in[12];
    float* out = (float*)d_out;

    char* p = (char*)d_ws;
    float* tswz = (float*)p; p += (long)NH * NI * NJ * sizeof(float);
    unsigned short* Wt_all   = (unsigned short*)p; p += 4 * 128 * 128 * sizeof(unsigned short);
    unsigned short* Wto      = (unsigned short*)p; p += 128 * 128 * sizeof(unsigned short);
    unsigned short* Wtri_pad = (unsigned short*)p; p += 32 * 128 * sizeof(unsigned short);

    hipLaunchKernelGGL(convert_weights, dim3(336), dim3(256), 0, stream,
                       wq, wk, wv, wg, wo, w_tri, Wt_all, Wto, Wtri_pad);
    hipLaunchKernelGGL(ln_tri, dim3(TOKS / 64), dim3(256), 0, stream,
                       x, ln_w, ln_b, Wtri_pad, tswz);
    hipLaunchKernelGGL(attn_mega, dim3(NI), dim3(512), 0, stream,
                       x, ln_w, ln_b, Wt_all, tswz, mask, Wto, bg, bo, out);
}